// Round 2
// baseline (246.767 us; speedup 1.0000x reference)
//
#include <hip/hip_runtime.h>
#include <math.h>

#define NB        50            // n_boundaries
#define ED        50            // EMBD_DIM
#define OD        50            // OUT_DIM
#define HID       101           // MLP width
#define KPAIR     128           // pair rows per bucket (dist intervals)
#define NBUCKET   49            // in-range buckets (idx in [1,49])
#define NPAIR     (NBUCKET * KPAIR) // 6272 in-range pair rows
#define NROWS     (NPAIR + 2)   // + oob0, oob1 rows (branch-free hot loop)
#define NP        (16 * 65536)  // B*N points
#define CHUNK     17            // pair rows per build block
#define NCHUNK    8             // ceil(128/17)
#define RU        26            // f16x4 units per row (25 valid + 1 pad) = 208 B
#define GU        13            // 16-B gather units per row

typedef float    f32x2 __attribute__((ext_vector_type(2)));
typedef _Float16 f16x2 __attribute__((ext_vector_type(2)));
typedef _Float16 f16x4 __attribute__((ext_vector_type(4)));
typedef _Float16 f16x8 __attribute__((ext_vector_type(8)));

// R9: 208-B paired rows (13 x 16-B units; unit u = components {4u..4u+3}
// stored as two f16x4 {a_lo,a_hi,b_lo,b_hi} pairs; unit 12 = comps 48,49 +
// 8-B zero pad). One dwordx4 gather now yields FOUR lerped outputs: 13
// gathers/point vs 25 dwordx2 (R8) vs 50 dword (R7). Plain stores again —
// nt evict-first is unneeded (table lines re-referenced ~4000x stay MRU in
// 4 MB L2) and nt is an unmeasured write-path risk. 6274 rows x 208 B =
// 1.30 MB, L2-resident per XCD. fp16 + interp err: absmax 1.95e-3, stable
// R5-R9 (identical table values; pad computed but never stored).
__device__ __align__(16) f16x4 g_pair[NROWS * RU];

// ---------------------------------------------------------------------------
// build_table: block = (bucket, 17-pair chunk), 392 blocks + 1 oob block.
// Phase 0: stage w1 in LDS, compute affine z(dist) = z0 + dist*c.
// Phase A: h[si][j] = gelu_exact(z) for 18 samples (17 pairs need k..k+17).
// Phase B: o-MAJOR dot assignment (o = d/18, si = d%18): w2s float4 reads
//          ~4-address near-broadcast (o*104 lane-stride was 16-way bank
//          conflict); hs reads ~4-way. Results to f16 LDS buffer.
// Phase C: pack {h_k, h_k+1} pairs -> g_pair (8-B stores), zero the pad unit.
// ---------------------------------------------------------------------------
__global__ __launch_bounds__(256) void build_table(
    const float* __restrict__ embd,
    const float* __restrict__ embd_oob,
    const float* __restrict__ w1,
    const float* __restrict__ b1,
    const float* __restrict__ w2,
    const float* __restrict__ b2)
{
    const int blk = blockIdx.x;
    const int t   = threadIdx.x;

    if (blk == NBUCKET * NCHUNK) {          // oob rows: a = b = oob value
        if (t < 2 * RU) {
            const int which = t / RU, c = t - which * RU;
            f16x4 vv;
            if (c == RU - 1) {              // pad unit
                vv.x = (_Float16)0.f; vv.y = (_Float16)0.f;
                vv.z = (_Float16)0.f; vv.w = (_Float16)0.f;
            } else {
                const float a0 = embd_oob[which * OD + 2 * c];
                const float a1 = embd_oob[which * OD + 2 * c + 1];
                vv.x = (_Float16)a0; vv.y = (_Float16)a1;
                vv.z = (_Float16)a0; vv.w = (_Float16)a1;
            }
            g_pair[(NPAIR + which) * RU + c] = vv;
        }
        return;
    }

    const int bu = blk >> 3;                // bucket
    const int ch = blk & 7;                 // chunk: pair rows k in [17ch, 17ch+16]

    __shared__ union U {
        float w1s[HID * HID];               // 40804 B (phase 0)
        struct {
            float    w2s[OD * 104];         // 20800 B
            float    hs[18 * 104];          // 7488 B (18 gelu sample rows)
            _Float16 hbuf[18 * 52];         // 1872 B (dot results, f16)
        } p;                                // 30160 B (A/B/C)
    } u;
    __shared__ float zc[224];               // z0 at [0..100], c at [112..212]

    for (int i = t; i < HID * HID; i += 256) u.w1s[i] = w1[i];
    __syncthreads();

    if (t < HID) {                          // affine z(dist) = z0 + dist*c
        const float* __restrict__ r  = u.w1s + t * HID;
        const float* __restrict__ ea = embd + (bu + 1) * ED;  // wave-uniform -> scalar loads
        float acc = b1[t];
        #pragma unroll 10
        for (int kk = 0; kk < ED; kk++)
            acc = fmaf(ea[kk], r[kk], fmaf(ea[ED + kk], r[ED + kk], acc));
        zc[t]       = acc;
        zc[112 + t] = r[2 * ED];
    }
    __syncthreads();                        // w1s reads done; reuse region

    for (int i = t; i < OD * HID; i += 256) {
        const int o = i / HID, j = i - o * HID;
        u.p.w2s[o * 104 + j] = w2[i];
    }

    #pragma unroll
    for (int si = 0; si < 18; si++) {       // 18 samples: pairs need k..k+1
        const int k = ch * CHUNK + si;
        if (t < HID && k <= 128) {
            const float dist = (float)k * (1.0f / 128.0f);
            const float z = fmaf(dist, zc[112 + t], zc[t]);
            u.p.hs[si * 104 + t] = 0.5f * z * (1.0f + erff(z * 0.70710678118654752f));
        }
    }
    __syncthreads();

    // Phase B: 900 dots (o in [0,50), si in [0,18)), o-major for bank health.
    // Out-of-range si (last chunk) compute garbage; phase C discards it.
    for (int dd = t; dd < 18 * OD; dd += 256) {
        const int o = dd / 18, si = dd - o * 18;
        float acc = b2[o];
        const float4* __restrict__ h4 = (const float4*)(u.p.hs  + si * 104);
        const float4* __restrict__ w4 = (const float4*)(u.p.w2s + o  * 104);
        #pragma unroll
        for (int jj = 0; jj < 25; jj++) {
            const float4 hh = h4[jj], ww = w4[jj];
            acc = fmaf(hh.x, ww.x, acc);
            acc = fmaf(hh.y, ww.y, acc);
            acc = fmaf(hh.z, ww.z, acc);
            acc = fmaf(hh.w, ww.w, acc);
        }
        acc = fmaf(u.p.hs[si * 104 + 100], u.p.w2s[o * 104 + 100], acc);
        u.p.hbuf[si * 52 + o] = (_Float16)acc;
    }
    __syncthreads();

    // Phase C: pack pair rows k = 17ch + si, si in [0,17), needs hbuf[si],[si+1].
    const f16x2* __restrict__ hb2 = (const f16x2*)u.p.hbuf;   // 26 f16x2/row
    for (int d = t; d < CHUNK * RU; d += 256) {
        const int si = d / RU, c = d - si * RU;
        const int k = ch * CHUNK + si;
        if (k <= 127) {
            f16x4 vv;
            if (c == RU - 1) {              // pad unit
                vv.x = (_Float16)0.f; vv.y = (_Float16)0.f;
                vv.z = (_Float16)0.f; vv.w = (_Float16)0.f;
            } else {
                const f16x2 a = hb2[si * 26 + c];
                const f16x2 b = hb2[(si + 1) * 26 + c];
                vv.x = a.x; vv.y = a.y; vv.z = b.x; vv.w = b.y;
            }
            g_pair[((bu * KPAIR + k) * RU) + c] = vv;
        }
    }
}

// ---------------------------------------------------------------------------
// main: block = 256 points (4096 blocks; R6 structure — persistent variant
// regressed in R7).
// Phase 1: per-thread searchsorted -> {gather_unit, frac} packed in one int2.
//          OOB points map to rows NPAIR/NPAIR+1 with frac = 0.
// Phase 2: branch-free: 13 iterations/thread, each 1 ds_read_b64 (broadcast)
//          + ONE dwordx4 gather (4 output comps, both lerp endpoints) + 4
//          f32 lerps + 2 plain f32x2 stores (pairs fill each other's 8-B
//          holes; full cachelines covered per wave). Unit 12's upper half is
//          pad: computed, never stored.
// ---------------------------------------------------------------------------
__global__ __launch_bounds__(256) void embed_main(
    const float* __restrict__ x,
    const float* __restrict__ boundaries,
    float* __restrict__ out)
{
    __shared__ float sB[NB];
    __shared__ int2  s_pk[256];             // {row*13, frac_bits}
    const int t = threadIdx.x;
    if (t < NB) sB[t] = boundaries[t];
    __syncthreads();

    const int p = blockIdx.x * 256 + t;
    const float xv = x[p];

    int   row;
    float frac = 0.0f;
    if (xv <= sB[0]) {                      // idx == 0  -> embd_oob[0]
        row = NPAIR;
    } else if (xv > sB[NB - 1]) {           // idx == 50 -> embd_oob[1]
        row = NPAIR + 1;
    } else {
        // linspace guess + 2-compare fixup = exact searchsorted 'left'
        int j = (int)(xv * 49.0f);
        if (j > 48) j = 48;
        const int idx = (xv > sB[j]) ? ((xv > sB[j + 1]) ? j + 2 : j + 1) : j;
        const float lo = sB[idx - 1];
        const float hi = sB[idx];
        const float dist = (xv - lo) / (hi - lo);   // same expr as reference
        const float tt = dist * 128.0f;             // dist in (0,1]
        int k0 = (int)tt;
        if (k0 > 127) k0 = 127;                     // dist==1 -> k0=127,frac=1
        frac = tt - (float)k0;
        row  = (idx - 1) * KPAIR + k0;              // pair row: {h_k0, h_k0+1}
    }
    s_pk[t] = make_int2(row * GU, __float_as_int(frac));
    __syncthreads();

    const f16x8* __restrict__ tabo = (const f16x8*)g_pair;   // 13 units/row
    f32x2* __restrict__ o2 = (f32x2*)out + (size_t)blockIdx.x * 6400;

    #pragma unroll
    for (int i = 0; i < 13; i++) {
        const int e  = i * 256 + t;         // gather-unit index in block (3328)
        const int pt = e / 13;              // point within block (magic mul)
        const int c4 = e - pt * 13;         // 16-B unit 0..12
        const int2 pk = s_pk[pt];           // one ds_read_b64 (broadcast)
        const float fr = __int_as_float(pk.y);
        const f16x8 v = tabo[pk.x + c4];    // one global dwordx4 gather
        const float a0 = (float)v[0], a1 = (float)v[1];
        const float b0 = (float)v[2], b1 = (float)v[3];
        const float a2 = (float)v[4], a3 = (float)v[5];
        const float b2v = (float)v[6], b3 = (float)v[7];
        f32x2 w0, w1;
        w0.x = fmaf(fr, b0 - a0, a0);
        w0.y = fmaf(fr, b1 - a1, a1);
        w1.x = fmaf(fr, b2v - a2, a2);
        w1.y = fmaf(fr, b3 - a3, a3);
        const int ob = pt * 25 + 2 * c4;    // f32x2 index (comps 4c4..4c4+3)
        o2[ob] = w0;
        if (c4 < 12) o2[ob + 1] = w1;       // unit 12 upper half = pad
    }
}

extern "C" void kernel_launch(void* const* d_in, const int* in_sizes, int n_in,
                              void* d_out, int out_size, void* d_ws, size_t ws_size,
                              hipStream_t stream) {
    const float* x    = (const float*)d_in[0];
    const float* bnd  = (const float*)d_in[1];
    const float* embd = (const float*)d_in[2];
    const float* oob  = (const float*)d_in[3];
    const float* w1   = (const float*)d_in[4];
    const float* b1   = (const float*)d_in[5];
    const float* w2   = (const float*)d_in[6];
    const float* b2   = (const float*)d_in[7];
    float* out = (float*)d_out;

    build_table<<<NBUCKET * NCHUNK + 1, 256, 0, stream>>>(embd, oob, w1, b1, w2, b2);
    embed_main<<<NP / 256, 256, 0, stream>>>(x, bnd, out);
}

// Round 3
// 244.596 us; speedup vs baseline: 1.0089x; 1.0089x over previous
//
#include <hip/hip_runtime.h>
#include <math.h>

#define NB        50            // n_boundaries
#define ED        50            // EMBD_DIM
#define OD        50            // OUT_DIM
#define HID       101           // MLP width
#define KPAIR     128           // pair rows per bucket (dist intervals)
#define NBUCKET   49            // in-range buckets (idx in [1,49])
#define NPAIR     (NBUCKET * KPAIR) // 6272 in-range pair rows
#define NROWS     (NPAIR + 2)   // + oob0, oob1 rows (branch-free hot loop)
#define NP        (16 * 65536)  // B*N points
#define CHUNK     17            // pair rows per build block
#define NCHUNK    8             // ceil(128/17)

typedef float    f32x2 __attribute__((ext_vector_type(2)));
typedef float    f32x4 __attribute__((ext_vector_type(4)));
typedef _Float16 f16x2 __attribute__((ext_vector_type(2)));
typedef _Float16 f16x4 __attribute__((ext_vector_type(4)));

// R10: back to R8's best-measured table layout: row = 25 x 8-B units,
// unit c = {a_2c, a_2c+1, b_2c, b_2c+1} (a = h_k0, b = h_k0+1), 200 B/row,
// 6274 rows = 1.25 MB, L2-resident. R9's 16-B gather + split-store variant
// REGRESSED ~10us: the two strided 8-B stores per lane doubled per-store
// cacheline touches — store density matters as much as gather count.
__device__ __align__(16) f16x4 g_pair[NROWS * 25];

// ---------------------------------------------------------------------------
// build_table: block = (bucket, 17-pair chunk), 392 blocks + 1 oob block.
// Phase 0: stage w1 in LDS, compute affine z(dist) = z0 + dist*c.
// Phase A: h[si][j] = gelu_exact(z) for 18 samples (17 pairs need k..k+17).
// Phase B: o-MAJOR dot assignment (o = d/18, si = d%18): w2s float4 reads
//          ~4-address near-broadcast; hs reads ~4-way. Results to f16 LDS.
// Phase C: pack {h_k, h_k+1} pairs -> g_pair (8-B stores).
// ---------------------------------------------------------------------------
__global__ __launch_bounds__(256) void build_table(
    const float* __restrict__ embd,
    const float* __restrict__ embd_oob,
    const float* __restrict__ w1,
    const float* __restrict__ b1,
    const float* __restrict__ w2,
    const float* __restrict__ b2)
{
    const int blk = blockIdx.x;
    const int t   = threadIdx.x;

    if (blk == NBUCKET * NCHUNK) {          // oob rows: a = b = oob value
        if (t < 2 * 25) {
            const int which = t / 25, c = t - which * 25;
            const float a0 = embd_oob[which * OD + 2 * c];
            const float a1 = embd_oob[which * OD + 2 * c + 1];
            f16x4 vv;
            vv.x = (_Float16)a0; vv.y = (_Float16)a1;
            vv.z = (_Float16)a0; vv.w = (_Float16)a1;
            g_pair[(NPAIR + which) * 25 + c] = vv;
        }
        return;
    }

    const int bu = blk >> 3;                // bucket
    const int ch = blk & 7;                 // chunk: pair rows k in [17ch, 17ch+16]

    __shared__ union U {
        float w1s[HID * HID];               // 40804 B (phase 0)
        struct {
            float    w2s[OD * 104];         // 20800 B
            float    hs[18 * 104];          // 7488 B (18 gelu sample rows)
            _Float16 hbuf[18 * 52];         // 1872 B (dot results, f16)
        } p;                                // 30160 B (A/B/C)
    } u;
    __shared__ float zc[224];               // z0 at [0..100], c at [112..212]

    for (int i = t; i < HID * HID; i += 256) u.w1s[i] = w1[i];
    __syncthreads();

    if (t < HID) {                          // affine z(dist) = z0 + dist*c
        const float* __restrict__ r  = u.w1s + t * HID;
        const float* __restrict__ ea = embd + (bu + 1) * ED;  // wave-uniform -> scalar loads
        float acc = b1[t];
        #pragma unroll 10
        for (int kk = 0; kk < ED; kk++)
            acc = fmaf(ea[kk], r[kk], fmaf(ea[ED + kk], r[ED + kk], acc));
        zc[t]       = acc;
        zc[112 + t] = r[2 * ED];
    }
    __syncthreads();                        // w1s reads done; reuse region

    for (int i = t; i < OD * HID; i += 256) {
        const int o = i / HID, j = i - o * HID;
        u.p.w2s[o * 104 + j] = w2[i];
    }

    #pragma unroll
    for (int si = 0; si < 18; si++) {       // 18 samples: pairs need k..k+1
        const int k = ch * CHUNK + si;
        if (t < HID && k <= 128) {
            const float dist = (float)k * (1.0f / 128.0f);
            const float z = fmaf(dist, zc[112 + t], zc[t]);
            u.p.hs[si * 104 + t] = 0.5f * z * (1.0f + erff(z * 0.70710678118654752f));
        }
    }
    __syncthreads();

    // Phase B: 900 dots (o in [0,50), si in [0,18)), o-major for bank health.
    // Out-of-range si (last chunk) compute garbage; phase C discards it.
    for (int dd = t; dd < 18 * OD; dd += 256) {
        const int o = dd / 18, si = dd - o * 18;
        float acc = b2[o];
        const float4* __restrict__ h4 = (const float4*)(u.p.hs  + si * 104);
        const float4* __restrict__ w4 = (const float4*)(u.p.w2s + o  * 104);
        #pragma unroll
        for (int jj = 0; jj < 25; jj++) {
            const float4 hh = h4[jj], ww = w4[jj];
            acc = fmaf(hh.x, ww.x, acc);
            acc = fmaf(hh.y, ww.y, acc);
            acc = fmaf(hh.z, ww.z, acc);
            acc = fmaf(hh.w, ww.w, acc);
        }
        acc = fmaf(u.p.hs[si * 104 + 100], u.p.w2s[o * 104 + 100], acc);
        u.p.hbuf[si * 52 + o] = (_Float16)acc;
    }
    __syncthreads();

    // Phase C: pack pair rows k = 17ch + si, si in [0,17), needs hbuf[si],[si+1].
    const f16x2* __restrict__ hb2 = (const f16x2*)u.p.hbuf;   // 26 f16x2/row
    for (int d = t; d < CHUNK * 25; d += 256) {
        const int si = d / 25, c = d - si * 25;
        const int k = ch * CHUNK + si;
        if (k <= 127) {
            const f16x2 a = hb2[si * 26 + c];
            const f16x2 b = hb2[(si + 1) * 26 + c];
            f16x4 vv;
            vv.x = a.x; vv.y = a.y; vv.z = b.x; vv.w = b.y;
            g_pair[((bu * KPAIR + k) * 25) + c] = vv;
        }
    }
}

// ---------------------------------------------------------------------------
// main: block = 256 points (4096 blocks).
// Phase 1: per-thread searchsorted -> {row*25, frac packed as f16x2} in int2.
//          OOB points map to rows NPAIR/NPAIR+1 with frac = 0.
// Phase 2: each lane produces ONE f32x4 output unit per iteration (12.5
//          iters/point vs R8's 25): 2 ds_read_b64 + 2 x 8-B gathers (same
//          count as R8, still semi-coalesced, alignment-safe) + packed-f16
//          lerp (v_pk ops) + ONE dense nontemporal dwordx4 store. The
//          point-boundary-crossing lane (rA==48, 1 in 25) runs the SAME
//          code path with pB=pA+1 — zero divergence. Stores per point
//          halve; magic-div/address VALU halves; lerp VALU ~halves.
// ---------------------------------------------------------------------------
__global__ __launch_bounds__(256) void embed_main(
    const float* __restrict__ x,
    const float* __restrict__ boundaries,
    float* __restrict__ out)
{
    __shared__ float sB[NB];
    __shared__ int2  s_pk[256];             // {row*25, frac as packed f16x2}
    const int t = threadIdx.x;
    if (t < NB) sB[t] = boundaries[t];
    __syncthreads();

    const int p = blockIdx.x * 256 + t;
    const float xv = x[p];

    int   row;
    float frac = 0.0f;
    if (xv <= sB[0]) {                      // idx == 0  -> embd_oob[0]
        row = NPAIR;
    } else if (xv > sB[NB - 1]) {           // idx == 50 -> embd_oob[1]
        row = NPAIR + 1;
    } else {
        // linspace guess + 2-compare fixup = exact searchsorted 'left'
        int j = (int)(xv * 49.0f);
        if (j > 48) j = 48;
        const int idx = (xv > sB[j]) ? ((xv > sB[j + 1]) ? j + 2 : j + 1) : j;
        const float lo = sB[idx - 1];
        const float hi = sB[idx];
        const float dist = (xv - lo) / (hi - lo);   // same expr as reference
        const float tt = dist * 128.0f;             // dist in (0,1]
        int k0 = (int)tt;
        if (k0 > 127) k0 = 127;                     // dist==1 -> k0=127,frac=1
        frac = tt - (float)k0;
        row  = (idx - 1) * KPAIR + k0;              // pair row: {h_k0, h_k0+1}
    }
    f16x2 fh; fh.x = (_Float16)frac; fh.y = fh.x;   // pre-packed lerp weight
    s_pk[t] = make_int2(row * 25, *(const int*)&fh);
    __syncthreads();

    const f16x4* __restrict__ tabp = g_pair;        // 25 units/row
    f32x4* __restrict__ o4 = (f32x4*)out + (size_t)blockIdx.x * 3200;

    #pragma unroll
    for (int i = 0; i < 13; i++) {
        const int e = i * 256 + t;          // f32x4 unit in block (3200 total)
        if (e < 3200) {                     // iter 12: waves 2,3 fully masked
            const int F  = 4 * e;           // f32 component base
            const int pA = (unsigned)F / 50u;       // magic mul
            const int rA = F - 50 * pA;             // 0..48, even
            const bool cross = (rA == 48);          // comps {48,49 | 0,1 of p+1}
            const int pB = cross ? pA + 1 : pA;     // crossing pA even -> pB<=255
            const int uB = cross ? 0 : (rA >> 1) + 1;
            const int2 ka = s_pk[pA];       // ds_read_b64, broadcast runs
            const int2 kb = s_pk[pB];
            const f16x4 va = tabp[ka.x + (rA >> 1)];  // 8-B gather
            const f16x4 vb = tabp[kb.x + uB];         // 8-B gather
            const f16x2 frA = *(const f16x2*)&ka.y;
            const f16x2 frB = *(const f16x2*)&kb.y;
            f16x2 a0; a0.x = va.x; a0.y = va.y;
            f16x2 b0; b0.x = va.z; b0.y = va.w;
            f16x2 a1; a1.x = vb.x; a1.y = vb.y;
            f16x2 b1; b1.x = vb.z; b1.y = vb.w;
            const f16x2 r0 = a0 + frA * (b0 - a0);  // v_pk_add/fma
            const f16x2 r1 = a1 + frB * (b1 - a1);
            f32x4 w;
            w.x = (float)r0.x; w.y = (float)r0.y;
            w.z = (float)r1.x; w.w = (float)r1.y;
            __builtin_nontemporal_store(w, &o4[e]); // dense dwordx4
        }
    }
}

extern "C" void kernel_launch(void* const* d_in, const int* in_sizes, int n_in,
                              void* d_out, int out_size, void* d_ws, size_t ws_size,
                              hipStream_t stream) {
    const float* x    = (const float*)d_in[0];
    const float* bnd  = (const float*)d_in[1];
    const float* embd = (const float*)d_in[2];
    const float* oob  = (const float*)d_in[3];
    const float* w1   = (const float*)d_in[4];
    const float* b1   = (const float*)d_in[5];
    const float* w2   = (const float*)d_in[6];
    const float* b2   = (const float*)d_in[7];
    float* out = (float*)d_out;

    build_table<<<NBUCKET * NCHUNK + 1, 256, 0, stream>>>(embd, oob, w1, b1, w2, b2);
    embed_main<<<NP / 256, 256, 0, stream>>>(x, bnd, out);
}

// Round 4
// 235.872 us; speedup vs baseline: 1.0462x; 1.0370x over previous
//
#include <hip/hip_runtime.h>
#include <math.h>

#define NB        50            // n_boundaries
#define ED        50            // EMBD_DIM
#define OD        50            // OUT_DIM
#define HID       101           // MLP width
#define KPAIR     128           // pair rows per bucket (dist intervals)
#define NBUCKET   49            // in-range buckets (idx in [1,49])
#define NPAIR     (NBUCKET * KPAIR) // 6272 in-range pair rows
#define NROWS     (NPAIR + 2)   // + oob0, oob1 rows (branch-free hot loop)
#define NP        (16 * 65536)  // B*N points
#define CHUNK     17            // pair rows per build block
#define NCHUNK    8             // ceil(128/17)

typedef float    f32x2 __attribute__((ext_vector_type(2)));
typedef float    f32x4 __attribute__((ext_vector_type(4)));
typedef _Float16 f16x2 __attribute__((ext_vector_type(2)));
typedef _Float16 f16x4 __attribute__((ext_vector_type(4)));

// Table: row = 25 x 8-B units, unit c = {a_2c, a_2c+1, b_2c, b_2c+1}
// (a = h_k0, b = h_k0+1), 200 B/row, 6274 rows = 1.25 MB, L2-resident.
// R11: structure frozen from R10; this round isolates LATENCY-HIDING:
// (1) __launch_bounds__(256,4) caps embed_main at 128 VGPR (>=16 waves/CU)
//     — the 13-deep unrolled gather loop may have pushed VGPR past 128,
//     collapsing occupancy (explains three consecutive instruction-count
//     nulls: R8/R9/R10 all ~115us vs ~35us memory floor);
// (2) plain stores (drop nt): the 6.8 TB/s fill kernel uses plain stores;
//     nt write-through on gfx950 is the only store-path difference left.
__device__ __align__(16) f16x4 g_pair[NROWS * 25];

// ---------------------------------------------------------------------------
// build_table: block = (bucket, 17-pair chunk), 392 blocks + 1 oob block.
// Phase 0: stage w1 in LDS, compute affine z(dist) = z0 + dist*c.
// Phase A: h[si][j] = gelu_exact(z) for 18 samples (17 pairs need k..k+17).
// Phase B: o-MAJOR dot assignment (o = d/18, si = d%18): w2s float4 reads
//          ~4-address near-broadcast; hs reads ~4-way. Results to f16 LDS.
// Phase C: pack {h_k, h_k+1} pairs -> g_pair (8-B stores).
// ---------------------------------------------------------------------------
__global__ __launch_bounds__(256) void build_table(
    const float* __restrict__ embd,
    const float* __restrict__ embd_oob,
    const float* __restrict__ w1,
    const float* __restrict__ b1,
    const float* __restrict__ w2,
    const float* __restrict__ b2)
{
    const int blk = blockIdx.x;
    const int t   = threadIdx.x;

    if (blk == NBUCKET * NCHUNK) {          // oob rows: a = b = oob value
        if (t < 2 * 25) {
            const int which = t / 25, c = t - which * 25;
            const float a0 = embd_oob[which * OD + 2 * c];
            const float a1 = embd_oob[which * OD + 2 * c + 1];
            f16x4 vv;
            vv.x = (_Float16)a0; vv.y = (_Float16)a1;
            vv.z = (_Float16)a0; vv.w = (_Float16)a1;
            g_pair[(NPAIR + which) * 25 + c] = vv;
        }
        return;
    }

    const int bu = blk >> 3;                // bucket
    const int ch = blk & 7;                 // chunk: pair rows k in [17ch, 17ch+16]

    __shared__ union U {
        float w1s[HID * HID];               // 40804 B (phase 0)
        struct {
            float    w2s[OD * 104];         // 20800 B
            float    hs[18 * 104];          // 7488 B (18 gelu sample rows)
            _Float16 hbuf[18 * 52];         // 1872 B (dot results, f16)
        } p;                                // 30160 B (A/B/C)
    } u;
    __shared__ float zc[224];               // z0 at [0..100], c at [112..212]

    for (int i = t; i < HID * HID; i += 256) u.w1s[i] = w1[i];
    __syncthreads();

    if (t < HID) {                          // affine z(dist) = z0 + dist*c
        const float* __restrict__ r  = u.w1s + t * HID;
        const float* __restrict__ ea = embd + (bu + 1) * ED;  // wave-uniform -> scalar loads
        float acc = b1[t];
        #pragma unroll 10
        for (int kk = 0; kk < ED; kk++)
            acc = fmaf(ea[kk], r[kk], fmaf(ea[ED + kk], r[ED + kk], acc));
        zc[t]       = acc;
        zc[112 + t] = r[2 * ED];
    }
    __syncthreads();                        // w1s reads done; reuse region

    for (int i = t; i < OD * HID; i += 256) {
        const int o = i / HID, j = i - o * HID;
        u.p.w2s[o * 104 + j] = w2[i];
    }

    #pragma unroll
    for (int si = 0; si < 18; si++) {       // 18 samples: pairs need k..k+1
        const int k = ch * CHUNK + si;
        if (t < HID && k <= 128) {
            const float dist = (float)k * (1.0f / 128.0f);
            const float z = fmaf(dist, zc[112 + t], zc[t]);
            u.p.hs[si * 104 + t] = 0.5f * z * (1.0f + erff(z * 0.70710678118654752f));
        }
    }
    __syncthreads();

    // Phase B: 900 dots (o in [0,50), si in [0,18)), o-major for bank health.
    // Out-of-range si (last chunk) compute garbage; phase C discards it.
    for (int dd = t; dd < 18 * OD; dd += 256) {
        const int o = dd / 18, si = dd - o * 18;
        float acc = b2[o];
        const float4* __restrict__ h4 = (const float4*)(u.p.hs  + si * 104);
        const float4* __restrict__ w4 = (const float4*)(u.p.w2s + o  * 104);
        #pragma unroll
        for (int jj = 0; jj < 25; jj++) {
            const float4 hh = h4[jj], ww = w4[jj];
            acc = fmaf(hh.x, ww.x, acc);
            acc = fmaf(hh.y, ww.y, acc);
            acc = fmaf(hh.z, ww.z, acc);
            acc = fmaf(hh.w, ww.w, acc);
        }
        acc = fmaf(u.p.hs[si * 104 + 100], u.p.w2s[o * 104 + 100], acc);
        u.p.hbuf[si * 52 + o] = (_Float16)acc;
    }
    __syncthreads();

    // Phase C: pack pair rows k = 17ch + si, si in [0,17), needs hbuf[si],[si+1].
    const f16x2* __restrict__ hb2 = (const f16x2*)u.p.hbuf;   // 26 f16x2/row
    for (int d = t; d < CHUNK * 25; d += 256) {
        const int si = d / 25, c = d - si * 25;
        const int k = ch * CHUNK + si;
        if (k <= 127) {
            const f16x2 a = hb2[si * 26 + c];
            const f16x2 b = hb2[(si + 1) * 26 + c];
            f16x4 vv;
            vv.x = a.x; vv.y = a.y; vv.z = b.x; vv.w = b.y;
            g_pair[((bu * KPAIR + k) * 25) + c] = vv;
        }
    }
}

// ---------------------------------------------------------------------------
// main: block = 256 points (4096 blocks).
// Phase 1: per-thread searchsorted -> {row*25, frac packed as f16x2} in int2.
//          OOB points map to rows NPAIR/NPAIR+1 with frac = 0.
// Phase 2: each lane produces ONE f32x4 output unit per iteration (12.5
//          iters/point): 2 ds_read_b64 + 2 x 8-B gathers + packed-f16 lerp
//          + ONE dense dwordx4 store. Crossing lane (rA==48, 1 in 25) runs
//          the same code path with pB=pA+1 — zero divergence.
// R11: __launch_bounds__(256,4) guarantees >=4 waves/SIMD (VGPR <= 128);
//      plain stores (nt dropped).
// ---------------------------------------------------------------------------
__global__ __launch_bounds__(256, 4) void embed_main(
    const float* __restrict__ x,
    const float* __restrict__ boundaries,
    float* __restrict__ out)
{
    __shared__ float sB[NB];
    __shared__ int2  s_pk[256];             // {row*25, frac as packed f16x2}
    const int t = threadIdx.x;
    if (t < NB) sB[t] = boundaries[t];
    __syncthreads();

    const int p = blockIdx.x * 256 + t;
    const float xv = x[p];

    int   row;
    float frac = 0.0f;
    if (xv <= sB[0]) {                      // idx == 0  -> embd_oob[0]
        row = NPAIR;
    } else if (xv > sB[NB - 1]) {           // idx == 50 -> embd_oob[1]
        row = NPAIR + 1;
    } else {
        // linspace guess + 2-compare fixup = exact searchsorted 'left'
        int j = (int)(xv * 49.0f);
        if (j > 48) j = 48;
        const int idx = (xv > sB[j]) ? ((xv > sB[j + 1]) ? j + 2 : j + 1) : j;
        const float lo = sB[idx - 1];
        const float hi = sB[idx];
        const float dist = (xv - lo) / (hi - lo);   // same expr as reference
        const float tt = dist * 128.0f;             // dist in (0,1]
        int k0 = (int)tt;
        if (k0 > 127) k0 = 127;                     // dist==1 -> k0=127,frac=1
        frac = tt - (float)k0;
        row  = (idx - 1) * KPAIR + k0;              // pair row: {h_k0, h_k0+1}
    }
    f16x2 fh; fh.x = (_Float16)frac; fh.y = fh.x;   // pre-packed lerp weight
    s_pk[t] = make_int2(row * 25, *(const int*)&fh);
    __syncthreads();

    const f16x4* __restrict__ tabp = g_pair;        // 25 units/row
    f32x4* __restrict__ o4 = (f32x4*)out + (size_t)blockIdx.x * 3200;

    #pragma unroll
    for (int i = 0; i < 13; i++) {
        const int e = i * 256 + t;          // f32x4 unit in block (3200 total)
        if (e < 3200) {                     // iter 12: waves 2,3 fully masked
            const int F  = 4 * e;           // f32 component base
            const int pA = (unsigned)F / 50u;       // magic mul
            const int rA = F - 50 * pA;             // 0..48, even
            const bool cross = (rA == 48);          // comps {48,49 | 0,1 of p+1}
            const int pB = cross ? pA + 1 : pA;     // crossing pA even -> pB<=255
            const int uB = cross ? 0 : (rA >> 1) + 1;
            const int2 ka = s_pk[pA];       // ds_read_b64, broadcast runs
            const int2 kb = s_pk[pB];
            const f16x4 va = tabp[ka.x + (rA >> 1)];  // 8-B gather
            const f16x4 vb = tabp[kb.x + uB];         // 8-B gather
            const f16x2 frA = *(const f16x2*)&ka.y;
            const f16x2 frB = *(const f16x2*)&kb.y;
            f16x2 a0; a0.x = va.x; a0.y = va.y;
            f16x2 b0; b0.x = va.z; b0.y = va.w;
            f16x2 a1; a1.x = vb.x; a1.y = vb.y;
            f16x2 b1; b1.x = vb.z; b1.y = vb.w;
            const f16x2 r0 = a0 + frA * (b0 - a0);  // v_pk_add/fma
            const f16x2 r1 = a1 + frB * (b1 - a1);
            f32x4 w;
            w.x = (float)r0.x; w.y = (float)r0.y;
            w.z = (float)r1.x; w.w = (float)r1.y;
            o4[e] = w;                      // dense dwordx4, plain store
        }
    }
}

extern "C" void kernel_launch(void* const* d_in, const int* in_sizes, int n_in,
                              void* d_out, int out_size, void* d_ws, size_t ws_size,
                              hipStream_t stream) {
    const float* x    = (const float*)d_in[0];
    const float* bnd  = (const float*)d_in[1];
    const float* embd = (const float*)d_in[2];
    const float* oob  = (const float*)d_in[3];
    const float* w1   = (const float*)d_in[4];
    const float* b1   = (const float*)d_in[5];
    const float* w2   = (const float*)d_in[6];
    const float* b2   = (const float*)d_in[7];
    float* out = (float*)d_out;

    build_table<<<NBUCKET * NCHUNK + 1, 256, 0, stream>>>(embd, oob, w1, b1, w2, b2);
    embed_main<<<NP / 256, 256, 0, stream>>>(x, bnd, out);
}

// Round 5
// 233.668 us; speedup vs baseline: 1.0561x; 1.0094x over previous
//
#include <hip/hip_runtime.h>
#include <math.h>

#define NB        50            // n_boundaries
#define ED        50            // EMBD_DIM
#define OD        50            // OUT_DIM
#define HID       101           // MLP width
#define KPAIR     128           // pair rows per bucket (dist intervals)
#define NBUCKET   49            // in-range buckets (idx in [1,49])
#define NPAIR     (NBUCKET * KPAIR) // 6272 in-range pair rows
#define NROWS     (NPAIR + 2)   // + oob0, oob1 rows (branch-free hot loop)
#define NP        (16 * 65536)  // B*N points
#define CHUNK     17            // pair rows per build block
#define NCHUNK    8             // ceil(128/17)

typedef float    f32x2 __attribute__((ext_vector_type(2)));
typedef float    f32x4 __attribute__((ext_vector_type(4)));
typedef _Float16 f16x2 __attribute__((ext_vector_type(2)));
typedef _Float16 f16x4 __attribute__((ext_vector_type(4)));

// Table: row = 25 x 8-B units, unit c = {a_2c, a_2c+1, b_2c, b_2c+1}
// (a = h_k0, b = h_k0+1), 200 B/row, 6274 rows = 1.25 MB, L2-resident.
// R12: embed_main frozen (R8-R11 all ~equal: gather/store/VALU/occupancy
// knobs exhausted, all null). This round targets build_table — the only
// never-measured, never-touched component. Its serial per-block chain
// (163 KB w1 staging -> sync -> 100-deep dot on 101 lanes -> sync -> 18
// erf on 101 lanes -> ...) at 3 blocks/CU residency could be the
// invariant ~tens-of-us slab masking every embed-side change.
__device__ __align__(16) f16x4 g_pair[NROWS * 25];

// ---------------------------------------------------------------------------
// build_table v2: block = (bucket, 17-pair chunk), 392 blocks + 1 oob block.
//  - NO w1 LDS staging: affine reads its w1 row direct from global (L2-hot;
//    392 blocks x 101 rows x 400 B = 16 MB L2 traffic), overlapped with the
//    w2 staging loads. Removes 160 loads/thread + 1 sync + 11 KB LDS.
//  - LDS 41.7 -> 31 KB: 5 blocks/CU co-resident (was 3) — grid rounds overlap.
//  - Phase A balanced over all 256 threads (erf/thread 18 -> ~7).
//  - Phase B (o-major, bank-healthy) and phase C unchanged.
// ---------------------------------------------------------------------------
__global__ __launch_bounds__(256) void build_table(
    const float* __restrict__ embd,
    const float* __restrict__ embd_oob,
    const float* __restrict__ w1,
    const float* __restrict__ b1,
    const float* __restrict__ w2,
    const float* __restrict__ b2)
{
    const int blk = blockIdx.x;
    const int t   = threadIdx.x;

    if (blk == NBUCKET * NCHUNK) {          // oob rows: a = b = oob value
        if (t < 2 * 25) {
            const int which = t / 25, c = t - which * 25;
            const float a0 = embd_oob[which * OD + 2 * c];
            const float a1 = embd_oob[which * OD + 2 * c + 1];
            f16x4 vv;
            vv.x = (_Float16)a0; vv.y = (_Float16)a1;
            vv.z = (_Float16)a0; vv.w = (_Float16)a1;
            g_pair[(NPAIR + which) * 25 + c] = vv;
        }
        return;
    }

    const int bu = blk >> 3;                // bucket
    const int ch = blk & 7;                 // chunk: pair rows k in [17ch, 17ch+16]

    __shared__ float    w2s[OD * 104];      // 20800 B
    __shared__ float    hs[18 * 104];       // 7488 B (18 gelu sample rows)
    __shared__ _Float16 hbuf[18 * 52];      // 1872 B (dot results, f16)
    __shared__ float    zc[224];            // z0 at [0..100], c at [112..212]

    // Stage w2 (coalesced) — issued first so it overlaps the affine below.
    for (int i = t; i < OD * HID; i += 256) {
        const int o = i / HID, j = i - o * HID;
        w2s[o * 104 + j] = w2[i];
    }

    if (t < HID) {                          // affine z(dist) = z0 + dist*c
        const float* __restrict__ r  = w1 + t * HID;          // direct global, L2-hot
        const float* __restrict__ ea = embd + (bu + 1) * ED;  // wave-uniform -> scalar loads
        float acc = b1[t];
        #pragma unroll 10
        for (int kk = 0; kk < ED; kk++)
            acc = fmaf(ea[kk], r[kk], fmaf(ea[ED + kk], r[ED + kk], acc));
        zc[t]       = acc;
        zc[112 + t] = r[2 * ED];
    }
    __syncthreads();

    // Phase A: 18 x 101 gelu samples, balanced over all 256 threads.
    for (int i = t; i < 18 * HID; i += 256) {
        const int si = i / HID, j = i - si * HID;
        const int k = ch * CHUNK + si;
        if (k <= 128) {
            const float dist = (float)k * (1.0f / 128.0f);
            const float z = fmaf(dist, zc[112 + j], zc[j]);
            hs[si * 104 + j] = 0.5f * z * (1.0f + erff(z * 0.70710678118654752f));
        }
    }
    __syncthreads();

    // Phase B: 900 dots (o in [0,50), si in [0,18)), o-major for bank health.
    // Out-of-range si (last chunk) compute garbage; phase C discards it.
    for (int dd = t; dd < 18 * OD; dd += 256) {
        const int o = dd / 18, si = dd - o * 18;
        float acc = b2[o];
        const float4* __restrict__ h4 = (const float4*)(hs  + si * 104);
        const float4* __restrict__ w4 = (const float4*)(w2s + o  * 104);
        #pragma unroll
        for (int jj = 0; jj < 25; jj++) {
            const float4 hh = h4[jj], ww = w4[jj];
            acc = fmaf(hh.x, ww.x, acc);
            acc = fmaf(hh.y, ww.y, acc);
            acc = fmaf(hh.z, ww.z, acc);
            acc = fmaf(hh.w, ww.w, acc);
        }
        acc = fmaf(hs[si * 104 + 100], w2s[o * 104 + 100], acc);
        hbuf[si * 52 + o] = (_Float16)acc;
    }
    __syncthreads();

    // Phase C: pack pair rows k = 17ch + si, si in [0,17), needs hbuf[si],[si+1].
    const f16x2* __restrict__ hb2 = (const f16x2*)hbuf;       // 26 f16x2/row
    for (int d = t; d < CHUNK * 25; d += 256) {
        const int si = d / 25, c = d - si * 25;
        const int k = ch * CHUNK + si;
        if (k <= 127) {
            const f16x2 a = hb2[si * 26 + c];
            const f16x2 b = hb2[(si + 1) * 26 + c];
            f16x4 vv;
            vv.x = a.x; vv.y = a.y; vv.z = b.x; vv.w = b.y;
            g_pair[((bu * KPAIR + k) * 25) + c] = vv;
        }
    }
}

// ---------------------------------------------------------------------------
// main: block = 256 points (4096 blocks). FROZEN from R11 (best measured).
// Phase 1: per-thread searchsorted -> {row*25, frac packed as f16x2} in int2.
//          OOB points map to rows NPAIR/NPAIR+1 with frac = 0.
// Phase 2: each lane produces ONE f32x4 output unit per iteration (12.5
//          iters/point): 2 ds_read_b64 + 2 x 8-B gathers + packed-f16 lerp
//          + ONE dense dwordx4 store. Crossing lane (rA==48, 1 in 25) runs
//          the same code path with pB=pA+1 — zero divergence.
// ---------------------------------------------------------------------------
__global__ __launch_bounds__(256, 4) void embed_main(
    const float* __restrict__ x,
    const float* __restrict__ boundaries,
    float* __restrict__ out)
{
    __shared__ float sB[NB];
    __shared__ int2  s_pk[256];             // {row*25, frac as packed f16x2}
    const int t = threadIdx.x;
    if (t < NB) sB[t] = boundaries[t];
    __syncthreads();

    const int p = blockIdx.x * 256 + t;
    const float xv = x[p];

    int   row;
    float frac = 0.0f;
    if (xv <= sB[0]) {                      // idx == 0  -> embd_oob[0]
        row = NPAIR;
    } else if (xv > sB[NB - 1]) {           // idx == 50 -> embd_oob[1]
        row = NPAIR + 1;
    } else {
        // linspace guess + 2-compare fixup = exact searchsorted 'left'
        int j = (int)(xv * 49.0f);
        if (j > 48) j = 48;
        const int idx = (xv > sB[j]) ? ((xv > sB[j + 1]) ? j + 2 : j + 1) : j;
        const float lo = sB[idx - 1];
        const float hi = sB[idx];
        const float dist = (xv - lo) / (hi - lo);   // same expr as reference
        const float tt = dist * 128.0f;             // dist in (0,1]
        int k0 = (int)tt;
        if (k0 > 127) k0 = 127;                     // dist==1 -> k0=127,frac=1
        frac = tt - (float)k0;
        row  = (idx - 1) * KPAIR + k0;              // pair row: {h_k0, h_k0+1}
    }
    f16x2 fh; fh.x = (_Float16)frac; fh.y = fh.x;   // pre-packed lerp weight
    s_pk[t] = make_int2(row * 25, *(const int*)&fh);
    __syncthreads();

    const f16x4* __restrict__ tabp = g_pair;        // 25 units/row
    f32x4* __restrict__ o4 = (f32x4*)out + (size_t)blockIdx.x * 3200;

    #pragma unroll
    for (int i = 0; i < 13; i++) {
        const int e = i * 256 + t;          // f32x4 unit in block (3200 total)
        if (e < 3200) {                     // iter 12: waves 2,3 fully masked
            const int F  = 4 * e;           // f32 component base
            const int pA = (unsigned)F / 50u;       // magic mul
            const int rA = F - 50 * pA;             // 0..48, even
            const bool cross = (rA == 48);          // comps {48,49 | 0,1 of p+1}
            const int pB = cross ? pA + 1 : pA;     // crossing pA even -> pB<=255
            const int uB = cross ? 0 : (rA >> 1) + 1;
            const int2 ka = s_pk[pA];       // ds_read_b64, broadcast runs
            const int2 kb = s_pk[pB];
            const f16x4 va = tabp[ka.x + (rA >> 1)];  // 8-B gather
            const f16x4 vb = tabp[kb.x + uB];         // 8-B gather
            const f16x2 frA = *(const f16x2*)&ka.y;
            const f16x2 frB = *(const f16x2*)&kb.y;
            f16x2 a0; a0.x = va.x; a0.y = va.y;
            f16x2 b0; b0.x = va.z; b0.y = va.w;
            f16x2 a1; a1.x = vb.x; a1.y = vb.y;
            f16x2 b1; b1.x = vb.z; b1.y = vb.w;
            const f16x2 r0 = a0 + frA * (b0 - a0);  // v_pk_add/fma
            const f16x2 r1 = a1 + frB * (b1 - a1);
            f32x4 w;
            w.x = (float)r0.x; w.y = (float)r0.y;
            w.z = (float)r1.x; w.w = (float)r1.y;
            o4[e] = w;                      // dense dwordx4, plain store
        }
    }
}

extern "C" void kernel_launch(void* const* d_in, const int* in_sizes, int n_in,
                              void* d_out, int out_size, void* d_ws, size_t ws_size,
                              hipStream_t stream) {
    const float* x    = (const float*)d_in[0];
    const float* bnd  = (const float*)d_in[1];
    const float* embd = (const float*)d_in[2];
    const float* oob  = (const float*)d_in[3];
    const float* w1   = (const float*)d_in[4];
    const float* b1   = (const float*)d_in[5];
    const float* w2   = (const float*)d_in[6];
    const float* b2   = (const float*)d_in[7];
    float* out = (float*)d_out;

    build_table<<<NBUCKET * NCHUNK + 1, 256, 0, stream>>>(embd, oob, w1, b1, w2, b2);
    embed_main<<<NP / 256, 256, 0, stream>>>(x, bnd, out);
}